// Round 1
// baseline (697.451 us; speedup 1.0000x reference)
//
#include <hip/hip_runtime.h>

// ---------------------------------------------------------------------------
// GCN encoder: h = relu(Agg(x@W1) + b1); [mu|lv] = Agg(h@[Wmu|Wlv]) + [bmu|blv]
// Agg(p)[i] = dinv[i] * ( sum_{e: dst=i} p[src_e]*dinv[src_e] + p[i]*dinv[i] )
// dinv[i] = rsqrt(indeg[i] + 1)   (self-loop included)
// CSR built once (count + scan + fill), gather aggregation (no fp atomics).
// ---------------------------------------------------------------------------

#define C_IN  256
#define HID   128
#define C_OUT 64

// ---------------- degree / dinv ----------------
__global__ void k_deg(const int* __restrict__ dst, int* __restrict__ deg, int E) {
  int e = blockIdx.x * blockDim.x + threadIdx.x;
  if (e < E) atomicAdd(&deg[dst[e]], 1);
}

__global__ void k_dinv(const int* __restrict__ deg, float* __restrict__ dinv, int n) {
  int i = blockIdx.x * blockDim.x + threadIdx.x;
  if (i < n) dinv[i] = rsqrtf((float)deg[i] + 1.0f);
}

// ---------------- 3-phase exclusive scan of deg -> row_start ----------------
__global__ void k_block_sum(const int* __restrict__ deg, int* __restrict__ bsum, int n) {
  __shared__ int sh[1024];
  int i = blockIdx.x * 1024 + threadIdx.x;
  sh[threadIdx.x] = (i < n) ? deg[i] : 0;
  __syncthreads();
  for (int s = 512; s > 0; s >>= 1) {
    if (threadIdx.x < s) sh[threadIdx.x] += sh[threadIdx.x + s];
    __syncthreads();
  }
  if (threadIdx.x == 0) bsum[blockIdx.x] = sh[0];
}

__global__ void k_scan_sums(int* __restrict__ bsum, int nb) {  // exclusive, in place
  __shared__ int sh[1024];
  int t = threadIdx.x;
  int v = (t < nb) ? bsum[t] : 0;
  sh[t] = v; __syncthreads();
  for (int ofs = 1; ofs < 1024; ofs <<= 1) {
    int add = (t >= ofs) ? sh[t - ofs] : 0;
    __syncthreads();
    sh[t] += add;
    __syncthreads();
  }
  if (t < nb) bsum[t] = sh[t] - v;
}

__global__ void k_scan_final(const int* __restrict__ deg, const int* __restrict__ bsum,
                             int* __restrict__ row_start, int n) {
  __shared__ int sh[1024];
  int t = threadIdx.x;
  int i = blockIdx.x * 1024 + t;
  int v = (i < n) ? deg[i] : 0;
  sh[t] = v; __syncthreads();
  for (int ofs = 1; ofs < 1024; ofs <<= 1) {
    int add = (t >= ofs) ? sh[t - ofs] : 0;
    __syncthreads();
    sh[t] += add;
    __syncthreads();
  }
  if (i < n) row_start[i] = bsum[blockIdx.x] + sh[t] - v;  // exclusive
}

__global__ void k_set1(int* p, int idx, int val) {
  if (blockIdx.x == 0 && threadIdx.x == 0) p[idx] = val;
}

__global__ void k_fill(const int* __restrict__ src, const int* __restrict__ dst,
                       const int* __restrict__ row_start, int* __restrict__ cursor,
                       int* __restrict__ csr_src, int E) {
  int e = blockIdx.x * blockDim.x + threadIdx.x;
  if (e < E) {
    int d = dst[e];
    int pos = atomicAdd(&cursor[d], 1);
    csr_src[row_start[d] + pos] = src[e];
  }
}

// ---------------- concat [Wmu | Wlv] -> W2 [128 x 128] ----------------
__global__ void k_w2cat(const float* __restrict__ Wmu, const float* __restrict__ Wlv,
                        float* __restrict__ w2) {
  int idx = blockIdx.x * blockDim.x + threadIdx.x;  // 128*128
  if (idx < HID * 128) {
    int k = idx >> 7, j = idx & 127;
    w2[idx] = (j < C_OUT) ? Wmu[k * C_OUT + j] : Wlv[k * C_OUT + (j - C_OUT)];
  }
}

// ---------------- fp32 tiled GEMM: C[M,128] = A[M,K] @ B[K,128] ----------------
// BM=64, BN=128, BK=8, 256 threads, 8x4 micro-tile (cols strided by 32).
#define BM 64
#define BN 128
#define BK 8
__global__ __launch_bounds__(256) void k_gemm(const float* __restrict__ A,
                                              const float* __restrict__ B,
                                              float* __restrict__ C, int M, int K) {
  __shared__ float As[BK][BM + 4];  // +4 pad: store pattern becomes <=2-way conflict
  __shared__ float Bs[BK][BN];
  int m0 = blockIdx.x * BM;
  int tid = threadIdx.x;
  int tcol = tid & 31;   // 32 col groups, cols tcol + 32*j
  int trow = tid >> 5;   // 8 row groups, rows trow*8 + i
  float acc[8][4] = {};
  for (int k0 = 0; k0 < K; k0 += BK) {
#pragma unroll
    for (int i = 0; i < 2; i++) {           // 512 A elems
      int idx = tid + i * 256;
      int r = idx >> 3, c = idx & 7;
      int gm = m0 + r;
      As[c][r] = (gm < M) ? A[(size_t)gm * K + k0 + c] : 0.f;
    }
#pragma unroll
    for (int i = 0; i < 4; i++) {           // 1024 B elems
      int idx = tid + i * 256;
      int kk = idx >> 7, nc = idx & 127;
      Bs[kk][nc] = B[(size_t)(k0 + kk) * BN + nc];
    }
    __syncthreads();
#pragma unroll
    for (int kk = 0; kk < BK; ++kk) {
      float a[8], b[4];
#pragma unroll
      for (int i = 0; i < 8; i++) a[i] = As[kk][trow * 8 + i];
#pragma unroll
      for (int j = 0; j < 4; j++) b[j] = Bs[kk][tcol + 32 * j];
#pragma unroll
      for (int i = 0; i < 8; i++)
#pragma unroll
        for (int j = 0; j < 4; j++) acc[i][j] += a[i] * b[j];
    }
    __syncthreads();
  }
#pragma unroll
  for (int i = 0; i < 8; i++) {
    int gm = m0 + trow * 8 + i;
    if (gm < M) {
#pragma unroll
      for (int j = 0; j < 4; j++) C[(size_t)gm * BN + tcol + 32 * j] = acc[i][j];
    }
  }
}

// ---------------- gather aggregation: one wave per node, 2 feats/lane ----------
#define AGG_BODY                                                                   \
  int wid = (blockIdx.x * blockDim.x + threadIdx.x) >> 6;                          \
  int lane = threadIdx.x & 63;                                                     \
  if (wid >= n) return;                                                            \
  int rs = row_start[wid], re = row_start[wid + 1];                                \
  float acc0 = 0.f, acc1 = 0.f;                                                    \
  int e = rs;                                                                      \
  for (; e + 4 <= re; e += 4) {                                                    \
    int s0 = csr[e], s1 = csr[e + 1], s2 = csr[e + 2], s3 = csr[e + 3];            \
    float w0 = dinv[s0], w1 = dinv[s1], w2 = dinv[s2], w3 = dinv[s3];              \
    const float* p0 = p + (size_t)s0 * 128 + lane;                                 \
    const float* p1 = p + (size_t)s1 * 128 + lane;                                 \
    const float* p2 = p + (size_t)s2 * 128 + lane;                                 \
    const float* p3 = p + (size_t)s3 * 128 + lane;                                 \
    float a0 = p0[0], c0 = p0[64], a1 = p1[0], c1 = p1[64];                        \
    float a2 = p2[0], c2 = p2[64], a3 = p3[0], c3 = p3[64];                        \
    acc0 += a0 * w0 + a1 * w1 + a2 * w2 + a3 * w3;                                 \
    acc1 += c0 * w0 + c1 * w1 + c2 * w2 + c3 * w3;                                 \
  }                                                                                \
  for (; e < re; ++e) {                                                            \
    int s = csr[e];                                                                \
    float w = dinv[s];                                                             \
    const float* ps = p + (size_t)s * 128 + lane;                                  \
    acc0 += ps[0] * w;                                                             \
    acc1 += ps[64] * w;                                                            \
  }                                                                                \
  float di = dinv[wid];                                                            \
  const float* pi = p + (size_t)wid * 128 + lane;                                  \
  acc0 = (acc0 + pi[0] * di) * di;                                                 \
  acc1 = (acc1 + pi[64] * di) * di;

__global__ __launch_bounds__(256) void k_agg_relu(
    const float* __restrict__ p, const float* __restrict__ dinv,
    const int* __restrict__ row_start, const int* __restrict__ csr,
    const float* __restrict__ bias, float* __restrict__ h, int n) {
  AGG_BODY
  float* ho = h + (size_t)wid * 128 + lane;
  ho[0]  = fmaxf(acc0 + bias[lane], 0.f);
  ho[64] = fmaxf(acc1 + bias[64 + lane], 0.f);
}

__global__ __launch_bounds__(256) void k_agg_out(
    const float* __restrict__ p, const float* __restrict__ dinv,
    const int* __restrict__ row_start, const int* __restrict__ csr,
    const float* __restrict__ bmu, const float* __restrict__ blv,
    float* __restrict__ out, int n) {
  AGG_BODY
  out[(size_t)wid * C_OUT + lane] = acc0 + bmu[lane];                    // mu
  out[(size_t)n * C_OUT + (size_t)wid * C_OUT + lane] = acc1 + blv[lane]; // logvar
}

// ---------------------------------------------------------------------------
extern "C" void kernel_launch(void* const* d_in, const int* in_sizes, int n_in,
                              void* d_out, int out_size, void* d_ws, size_t ws_size,
                              hipStream_t stream) {
  const float* x   = (const float*)d_in[0];
  const int*   ei  = (const int*)d_in[1];   // int32 on the wire (JAX x64 off)
  const float* W1  = (const float*)d_in[2];
  const float* b1  = (const float*)d_in[3];
  const float* Wmu = (const float*)d_in[4];
  const float* bmu = (const float*)d_in[5];
  const float* Wlv = (const float*)d_in[6];
  const float* blv = (const float*)d_in[7];
  float* out = (float*)d_out;

  const int n = in_sizes[0] / C_IN;
  const int E = in_sizes[1] / 2;
  const int* src = ei;
  const int* dst = ei + E;

  // workspace carve-up (256B aligned)
  char* w = (char*)d_ws;
  auto alloc = [&](size_t bytes) -> void* {
    void* pp = (void*)w;
    w += (bytes + 255) & ~(size_t)255;
    return pp;
  };
  int*   degi      = (int*)alloc((size_t)n * 4);        // later reused as fill cursor
  float* dinv      = (float*)alloc((size_t)n * 4);
  int*   row_start = (int*)alloc((size_t)(n + 1) * 4);
  int*   bsum      = (int*)alloc(1024 * 4);
  int*   csr_src   = (int*)alloc((size_t)E * 4);
  float* w2        = (float*)alloc((size_t)HID * 128 * 4);
  float* bufA      = (float*)alloc((size_t)n * 128 * 4);
  float* bufB      = (float*)alloc((size_t)n * 128 * 4);
  (void)ws_size; (void)n_in; (void)out_size;

  const int TB = 256;
  const int ebks = (E + TB - 1) / TB;
  const int nbks = (n + TB - 1) / TB;
  const int nb_scan = (n + 1023) / 1024;
  const int gemm_bks = (n + BM - 1) / BM;
  const int agg_bks = (n * 64 + TB - 1) / TB;  // one wave (64 lanes) per node

  // ---- graph structure (once per launch) ----
  hipMemsetAsync(degi, 0, (size_t)n * 4, stream);
  k_deg<<<ebks, TB, 0, stream>>>(dst, degi, E);
  k_dinv<<<nbks, TB, 0, stream>>>(degi, dinv, n);
  k_block_sum<<<nb_scan, 1024, 0, stream>>>(degi, bsum, n);
  k_scan_sums<<<1, 1024, 0, stream>>>(bsum, nb_scan);
  k_scan_final<<<nb_scan, 1024, 0, stream>>>(degi, bsum, row_start, n);
  k_set1<<<1, 1, 0, stream>>>(row_start, n, E);
  hipMemsetAsync(degi, 0, (size_t)n * 4, stream);      // reuse as cursor
  k_fill<<<ebks, TB, 0, stream>>>(src, dst, row_start, degi, csr_src, E);
  k_w2cat<<<(HID * 128 + TB - 1) / TB, TB, 0, stream>>>(Wmu, Wlv, w2);

  // ---- layer 1: h = relu(Agg(x@W1) + b1) ----
  k_gemm<<<gemm_bks, TB, 0, stream>>>(x, W1, bufA, n, C_IN);           // bufA = x@W1
  k_agg_relu<<<agg_bks, TB, 0, stream>>>(bufA, dinv, row_start, csr_src, b1, bufB, n);

  // ---- layer 2+3 fused: [mu|lv] = Agg(h@[Wmu|Wlv]) + bias ----
  k_gemm<<<gemm_bks, TB, 0, stream>>>(bufB, w2, bufA, n, HID);         // bufA = h@W2
  k_agg_out<<<agg_bks, TB, 0, stream>>>(bufA, dinv, row_start, csr_src, bmu, blv, out, n);
}

// Round 2
// 531.606 us; speedup vs baseline: 1.3120x; 1.3120x over previous
//
#include <hip/hip_runtime.h>

// ---------------------------------------------------------------------------
// GCN encoder, bf16 edition:
//   h  = relu(Agg(x@W1) + b1)          [bf16 staging, fp32 accumulate]
//   [mu|lv] = Agg(h@[Wmu|Wlv]) + bias  [fp32 output]
// Agg(p)[i] = dinv[i] * ( sum_{e: dst=i} p[src]*dinv[src] + p[i]*dinv[i] )
// GEMMs: mfma_f32_16x16x32_bf16, no LDS (A frags contiguous from global,
// B pre-swizzled into per-lane fragment order, L2-resident).
// Aggregation: gather over CSR, 1 dword (2 bf16) per lane per edge.
// ---------------------------------------------------------------------------

#define C_IN  256
#define HID   128
#define C_OUT 64

typedef __attribute__((ext_vector_type(8))) short bf16x8;
typedef __attribute__((ext_vector_type(4))) float f32x4;

__device__ inline unsigned short f2bf(float f) {  // round-to-nearest-even
  unsigned u = __float_as_uint(f);
  unsigned r = u + 0x7FFF + ((u >> 16) & 1);
  return (unsigned short)(r >> 16);
}
__device__ inline float bflo(unsigned v) { return __uint_as_float(v << 16); }
__device__ inline float bfhi(unsigned v) { return __uint_as_float(v & 0xFFFF0000u); }

// ---------------- degree / dinv ----------------
__global__ void k_deg(const int* __restrict__ dst, int* __restrict__ deg, int E) {
  int e = blockIdx.x * blockDim.x + threadIdx.x;
  if (e < E) atomicAdd(&deg[dst[e]], 1);
}

__global__ void k_dinv(const int* __restrict__ deg, float* __restrict__ dinv, int n) {
  int i = blockIdx.x * blockDim.x + threadIdx.x;
  if (i < n) dinv[i] = rsqrtf((float)deg[i] + 1.0f);
}

// ---------------- 3-phase exclusive scan of deg -> row_start ----------------
__global__ void k_block_sum(const int* __restrict__ deg, int* __restrict__ bsum, int n) {
  __shared__ int sh[1024];
  int i = blockIdx.x * 1024 + threadIdx.x;
  sh[threadIdx.x] = (i < n) ? deg[i] : 0;
  __syncthreads();
  for (int s = 512; s > 0; s >>= 1) {
    if (threadIdx.x < s) sh[threadIdx.x] += sh[threadIdx.x + s];
    __syncthreads();
  }
  if (threadIdx.x == 0) bsum[blockIdx.x] = sh[0];
}

__global__ void k_scan_sums(int* __restrict__ bsum, int nb) {  // exclusive, in place
  __shared__ int sh[1024];
  int t = threadIdx.x;
  int v = (t < nb) ? bsum[t] : 0;
  sh[t] = v; __syncthreads();
  for (int ofs = 1; ofs < 1024; ofs <<= 1) {
    int add = (t >= ofs) ? sh[t - ofs] : 0;
    __syncthreads();
    sh[t] += add;
    __syncthreads();
  }
  if (t < nb) bsum[t] = sh[t] - v;
}

__global__ void k_scan_final(const int* __restrict__ deg, const int* __restrict__ bsum,
                             int* __restrict__ row_start, int n) {
  __shared__ int sh[1024];
  int t = threadIdx.x;
  int i = blockIdx.x * 1024 + t;
  int v = (i < n) ? deg[i] : 0;
  sh[t] = v; __syncthreads();
  for (int ofs = 1; ofs < 1024; ofs <<= 1) {
    int add = (t >= ofs) ? sh[t - ofs] : 0;
    __syncthreads();
    sh[t] += add;
    __syncthreads();
  }
  if (i < n) row_start[i] = bsum[blockIdx.x] + sh[t] - v;  // exclusive
}

__global__ void k_set1(int* p, int idx, int val) {
  if (blockIdx.x == 0 && threadIdx.x == 0) p[idx] = val;
}

__global__ void k_fill(const int* __restrict__ src, const int* __restrict__ dst,
                       const int* __restrict__ row_start, int* __restrict__ cursor,
                       int* __restrict__ csr_src, int E) {
  int e = blockIdx.x * blockDim.x + threadIdx.x;
  if (e < E) {
    int d = dst[e];
    int pos = atomicAdd(&cursor[d], 1);
    csr_src[row_start[d] + pos] = src[e];
  }
}

// ---------------- B pre-swizzle into MFMA fragment order ----------------
// Bswz[s][t][L][j] = bf16( B[s*32 + (L>>4)*8 + j][t*16 + (L&15)] )
// so lane L's B-frag for k-step s, n-tile t is 8 contiguous bf16 (one dwordx4).
__global__ void k_prep_b1(const float* __restrict__ W1, unsigned short* __restrict__ bswz) {
  int idx = blockIdx.x * 256 + threadIdx.x;  // (256/32)*8*64 = 4096
  if (idx >= 4096) return;
  int L = idx & 63, t = (idx >> 6) & 7, s = idx >> 9;
  const float* srcp = W1 + (size_t)(s * 32 + ((L >> 4) << 3)) * 128 + t * 16 + (L & 15);
  unsigned short* dstp = bswz + (size_t)idx * 8;
#pragma unroll
  for (int j = 0; j < 8; j++) dstp[j] = f2bf(srcp[(size_t)j * 128]);
}

// W2 = [Wmu | Wlv] (128 x 128), swizzled the same way.
__global__ void k_prep_b2(const float* __restrict__ Wmu, const float* __restrict__ Wlv,
                          unsigned short* __restrict__ bswz) {
  int idx = blockIdx.x * 256 + threadIdx.x;  // (128/32)*8*64 = 2048
  if (idx >= 2048) return;
  int L = idx & 63, t = (idx >> 6) & 7, s = idx >> 9;
  int nn = t * 16 + (L & 15);
  int k0 = s * 32 + ((L >> 4) << 3);
  const float* W = (nn < C_OUT) ? (Wmu + nn) : (Wlv + (nn - C_OUT));
  unsigned short* dstp = bswz + (size_t)idx * 8;
#pragma unroll
  for (int j = 0; j < 8; j++) dstp[j] = f2bf(W[(size_t)(k0 + j) * C_OUT]);
}

// ---------------- MFMA GEMM: C[M,128](bf16) = A[M,K] @ B[K,128] ----------------
// 256 thr = 4 waves; wave w owns rows m0+16w..+15; 8 n-tiles of 16; BK=32.
// A frag straight from global (8 contiguous k-elems per lane); B from Bswz.
template <typename AT>
__global__ __launch_bounds__(256) void k_gemm_mfma(const AT* __restrict__ A,
                                                   const unsigned short* __restrict__ bswz,
                                                   unsigned short* __restrict__ C,
                                                   int M, int K) {
  int wave = threadIdx.x >> 6, lane = threadIdx.x & 63;
  int m0 = blockIdx.x * 64 + wave * 16;
  int lrow = lane & 15, lq = lane >> 4;
  int arow = m0 + lrow;
  bool rv = arow < M;
  const AT* ap = A + (size_t)(rv ? arow : 0) * K + lq * 8;
  f32x4 acc[8];
#pragma unroll
  for (int t = 0; t < 8; t++) acc[t] = (f32x4){0.f, 0.f, 0.f, 0.f};
  int nsteps = K >> 5;
  for (int s = 0; s < nsteps; ++s) {
    bf16x8 a;
    if (sizeof(AT) == 4) {  // fp32 A -> convert
      const float* af = (const float*)ap + s * 32;
      float4 u0 = rv ? *(const float4*)(af) : float4{0, 0, 0, 0};
      float4 u1 = rv ? *(const float4*)(af + 4) : float4{0, 0, 0, 0};
      union { unsigned short us[8]; bf16x8 v; } tmp;
      tmp.us[0] = f2bf(u0.x); tmp.us[1] = f2bf(u0.y);
      tmp.us[2] = f2bf(u0.z); tmp.us[3] = f2bf(u0.w);
      tmp.us[4] = f2bf(u1.x); tmp.us[5] = f2bf(u1.y);
      tmp.us[6] = f2bf(u1.z); tmp.us[7] = f2bf(u1.w);
      a = tmp.v;
    } else {               // bf16 A
      const unsigned short* ab = (const unsigned short*)ap + s * 32;
      a = rv ? *(const bf16x8*)(ab) : (bf16x8)(short)0;
    }
    const unsigned short* bp = bswz + (size_t)s * 4096 + lane * 8;
#pragma unroll
    for (int t = 0; t < 8; t++) {
      bf16x8 b = *(const bf16x8*)(bp + t * 512);
      acc[t] = __builtin_amdgcn_mfma_f32_16x16x32_bf16(a, b, acc[t], 0, 0, 0);
    }
  }
  // epilogue: D row = lq*4 + i (within wave tile), col = t*16 + lrow
#pragma unroll
  for (int i = 0; i < 4; i++) {
    int rr = m0 + lq * 4 + i;
    if (rr < M) {
      unsigned short* cp = C + (size_t)rr * 128 + lrow;
#pragma unroll
      for (int t = 0; t < 8; t++) cp[t * 16] = f2bf(acc[t][i]);
    }
  }
}

// ---------------- gather aggregation, bf16 features, 1 dword/lane/edge --------
#define AGG_BODY                                                                    \
  int wid = (blockIdx.x * blockDim.x + threadIdx.x) >> 6;                           \
  int lane = threadIdx.x & 63;                                                      \
  if (wid >= n) return;                                                             \
  int rs = row_start[wid], re = row_start[wid + 1];                                 \
  float acc0 = 0.f, acc1 = 0.f;                                                     \
  int e = rs;                                                                       \
  for (; e + 8 <= re; e += 8) {                                                     \
    float pa0, pa1, pa2, pa3, pa4, pa5, pa6, pa7;                                   \
    float pb0, pb1, pb2, pb3, pb4, pb5, pb6, pb7;                                   \
    float w0, w1, w2, w3, w4, w5, w6, w7;                                           \
    {                                                                               \
      int s0 = csr[e], s1 = csr[e+1], s2 = csr[e+2], s3 = csr[e+3];                 \
      int s4 = csr[e+4], s5 = csr[e+5], s6 = csr[e+6], s7 = csr[e+7];               \
      w0 = dinv[s0]; w1 = dinv[s1]; w2 = dinv[s2]; w3 = dinv[s3];                   \
      w4 = dinv[s4]; w5 = dinv[s5]; w6 = dinv[s6]; w7 = dinv[s7];                   \
      unsigned v0 = *(const unsigned*)(p + (size_t)s0 * 128 + 2 * lane);            \
      unsigned v1 = *(const unsigned*)(p + (size_t)s1 * 128 + 2 * lane);            \
      unsigned v2 = *(const unsigned*)(p + (size_t)s2 * 128 + 2 * lane);            \
      unsigned v3 = *(const unsigned*)(p + (size_t)s3 * 128 + 2 * lane);            \
      unsigned v4 = *(const unsigned*)(p + (size_t)s4 * 128 + 2 * lane);            \
      unsigned v5 = *(const unsigned*)(p + (size_t)s5 * 128 + 2 * lane);            \
      unsigned v6 = *(const unsigned*)(p + (size_t)s6 * 128 + 2 * lane);            \
      unsigned v7 = *(const unsigned*)(p + (size_t)s7 * 128 + 2 * lane);            \
      pa0 = bflo(v0); pb0 = bfhi(v0); pa1 = bflo(v1); pb1 = bfhi(v1);               \
      pa2 = bflo(v2); pb2 = bfhi(v2); pa3 = bflo(v3); pb3 = bfhi(v3);               \
      pa4 = bflo(v4); pb4 = bfhi(v4); pa5 = bflo(v5); pb5 = bfhi(v5);               \
      pa6 = bflo(v6); pb6 = bfhi(v6); pa7 = bflo(v7); pb7 = bfhi(v7);               \
    }                                                                               \
    acc0 += pa0*w0 + pa1*w1 + pa2*w2 + pa3*w3 + pa4*w4 + pa5*w5 + pa6*w6 + pa7*w7;  \
    acc1 += pb0*w0 + pb1*w1 + pb2*w2 + pb3*w3 + pb4*w4 + pb5*w5 + pb6*w6 + pb7*w7;  \
  }                                                                                 \
  for (; e < re; ++e) {                                                             \
    int s = csr[e];                                                                 \
    float w = dinv[s];                                                              \
    unsigned v = *(const unsigned*)(p + (size_t)s * 128 + 2 * lane);                \
    acc0 += bflo(v) * w;                                                            \
    acc1 += bfhi(v) * w;                                                            \
  }                                                                                 \
  float di = dinv[wid];                                                             \
  unsigned vi = *(const unsigned*)(p + (size_t)wid * 128 + 2 * lane);               \
  acc0 = (acc0 + bflo(vi) * di) * di;                                               \
  acc1 = (acc1 + bfhi(vi) * di) * di;

__global__ __launch_bounds__(256) void k_agg_relu_bf(
    const unsigned short* __restrict__ p, const float* __restrict__ dinv,
    const int* __restrict__ row_start, const int* __restrict__ csr,
    const float* __restrict__ bias, unsigned short* __restrict__ h, int n) {
  AGG_BODY
  float2 bb = *(const float2*)(bias + 2 * lane);
  float r0 = fmaxf(acc0 + bb.x, 0.f);
  float r1 = fmaxf(acc1 + bb.y, 0.f);
  unsigned pk = (unsigned)f2bf(r0) | ((unsigned)f2bf(r1) << 16);
  *(unsigned*)(h + (size_t)wid * 128 + 2 * lane) = pk;
}

__global__ __launch_bounds__(256) void k_agg_out_bf(
    const unsigned short* __restrict__ p, const float* __restrict__ dinv,
    const int* __restrict__ row_start, const int* __restrict__ csr,
    const float* __restrict__ bmu, const float* __restrict__ blv,
    float* __restrict__ out, int n) {
  AGG_BODY
  // lane cols 2L,2L+1: L<32 -> mu cols, L>=32 -> lv cols
  float2 bb = (lane < 32) ? *(const float2*)(bmu + 2 * lane)
                          : *(const float2*)(blv + 2 * lane - 64);
  size_t base = (lane < 32) ? ((size_t)wid * C_OUT + 2 * lane)
                            : ((size_t)(n + wid) * C_OUT + 2 * lane - 64);
  float2 res = {acc0 + bb.x, acc1 + bb.y};
  *(float2*)(out + base) = res;
}

// ---------------------------------------------------------------------------
extern "C" void kernel_launch(void* const* d_in, const int* in_sizes, int n_in,
                              void* d_out, int out_size, void* d_ws, size_t ws_size,
                              hipStream_t stream) {
  const float* x   = (const float*)d_in[0];
  const int*   ei  = (const int*)d_in[1];   // int32 on the wire (JAX x64 off)
  const float* W1  = (const float*)d_in[2];
  const float* b1  = (const float*)d_in[3];
  const float* Wmu = (const float*)d_in[4];
  const float* bmu = (const float*)d_in[5];
  const float* Wlv = (const float*)d_in[6];
  const float* blv = (const float*)d_in[7];
  float* out = (float*)d_out;

  const int n = in_sizes[0] / C_IN;
  const int E = in_sizes[1] / 2;
  const int* src = ei;
  const int* dst = ei + E;

  // workspace carve-up (256B aligned)
  char* w = (char*)d_ws;
  auto alloc = [&](size_t bytes) -> void* {
    void* pp = (void*)w;
    w += (bytes + 255) & ~(size_t)255;
    return pp;
  };
  int*            degi      = (int*)alloc((size_t)n * 4);       // reused as fill cursor
  float*          dinv      = (float*)alloc((size_t)n * 4);
  int*            row_start = (int*)alloc((size_t)(n + 1) * 4);
  int*            bsum      = (int*)alloc(1024 * 4);
  int*            csr_src   = (int*)alloc((size_t)E * 4);
  unsigned short* bswz1     = (unsigned short*)alloc((size_t)C_IN * 128 * 2);
  unsigned short* bswz2     = (unsigned short*)alloc((size_t)HID * 128 * 2);
  unsigned short* p1        = (unsigned short*)alloc((size_t)n * 128 * 2);
  unsigned short* hbuf      = (unsigned short*)alloc((size_t)n * 128 * 2);
  unsigned short* p2        = (unsigned short*)alloc((size_t)n * 128 * 2);
  (void)ws_size; (void)n_in; (void)out_size;

  const int TB = 256;
  const int ebks = (E + TB - 1) / TB;
  const int nbks = (n + TB - 1) / TB;
  const int nb_scan = (n + 1023) / 1024;
  const int gemm_bks = (n + 63) / 64;
  const int agg_bks = (int)(((size_t)n * 64 + TB - 1) / TB);  // one wave per node

  // ---- graph structure ----
  hipMemsetAsync(degi, 0, (size_t)n * 4, stream);
  k_deg<<<ebks, TB, 0, stream>>>(dst, degi, E);
  k_dinv<<<nbks, TB, 0, stream>>>(degi, dinv, n);
  k_block_sum<<<nb_scan, 1024, 0, stream>>>(degi, bsum, n);
  k_scan_sums<<<1, 1024, 0, stream>>>(bsum, nb_scan);
  k_scan_final<<<nb_scan, 1024, 0, stream>>>(degi, bsum, row_start, n);
  k_set1<<<1, 1, 0, stream>>>(row_start, n, E);
  hipMemsetAsync(degi, 0, (size_t)n * 4, stream);  // reuse as cursor
  k_fill<<<ebks, TB, 0, stream>>>(src, dst, row_start, degi, csr_src, E);

  // ---- weight pre-swizzle (bf16 fragment order) ----
  k_prep_b1<<<16, 256, 0, stream>>>(W1, bswz1);
  k_prep_b2<<<8, 256, 0, stream>>>(Wmu, Wlv, bswz2);

  // ---- layer 1 ----
  k_gemm_mfma<float><<<gemm_bks, TB, 0, stream>>>(x, bswz1, p1, n, C_IN);
  k_agg_relu_bf<<<agg_bks, TB, 0, stream>>>(p1, dinv, row_start, csr_src, b1, hbuf, n);

  // ---- layer 2+3 fused ----
  k_gemm_mfma<unsigned short><<<gemm_bks, TB, 0, stream>>>(hbuf, bswz2, p2, n, HID);
  k_agg_out_bf<<<agg_bks, TB, 0, stream>>>(p2, dinv, row_start, csr_src, bmu, blv, out, n);
}

// Round 3
// 493.235 us; speedup vs baseline: 1.4140x; 1.0778x over previous
//
#include <hip/hip_runtime.h>

// ---------------------------------------------------------------------------
// GCN encoder, bf16 staging + MFMA GEMMs + half-wave-per-edge gather agg.
//   h  = relu(Agg(x@W1) + b1);  [mu|lv] = Agg(h@[Wmu|Wlv]) + bias
// Agg(p)[i] = dinv[i] * ( sum_{e: dst=i} p[src]*dinv[src] + p[i]*dinv[i] )
// CSR build: count-with-position (one atomic pass) + scan + atomic-free scatter.
// Agg: one wave per node, 2 edges/iter (32 lanes x 4 bf16 feats each),
//      unroll 8 pairs = 16 edges in flight, __shfl_xor(32) final reduce.
// ---------------------------------------------------------------------------

#define C_IN  256
#define HID   128
#define C_OUT 64

typedef __attribute__((ext_vector_type(8))) short bf16x8;
typedef __attribute__((ext_vector_type(4))) float f32x4;

__device__ inline unsigned short f2bf(float f) {  // round-to-nearest-even
  unsigned u = __float_as_uint(f);
  unsigned r = u + 0x7FFF + ((u >> 16) & 1);
  return (unsigned short)(r >> 16);
}
__device__ inline float bflo(unsigned v) { return __uint_as_float(v << 16); }
__device__ inline float bfhi(unsigned v) { return __uint_as_float(v & 0xFFFF0000u); }

// ---------------- degree count + fill position (one atomic pass) ------------
__global__ void k_count(const int* __restrict__ dst, int* __restrict__ deg,
                        int* __restrict__ pos, int E) {
  int e = blockIdx.x * blockDim.x + threadIdx.x;
  if (e < E) pos[e] = atomicAdd(&deg[dst[e]], 1);
}

__global__ void k_dinv(const int* __restrict__ deg, float* __restrict__ dinv, int n) {
  int i = blockIdx.x * blockDim.x + threadIdx.x;
  if (i < n) dinv[i] = rsqrtf((float)deg[i] + 1.0f);
}

// ---------------- 3-phase exclusive scan of deg -> row_start ----------------
__global__ void k_block_sum(const int* __restrict__ deg, int* __restrict__ bsum, int n) {
  __shared__ int sh[1024];
  int i = blockIdx.x * 1024 + threadIdx.x;
  sh[threadIdx.x] = (i < n) ? deg[i] : 0;
  __syncthreads();
  for (int s = 512; s > 0; s >>= 1) {
    if (threadIdx.x < s) sh[threadIdx.x] += sh[threadIdx.x + s];
    __syncthreads();
  }
  if (threadIdx.x == 0) bsum[blockIdx.x] = sh[0];
}

__global__ void k_scan_sums(int* __restrict__ bsum, int nb) {  // exclusive, in place
  __shared__ int sh[1024];
  int t = threadIdx.x;
  int v = (t < nb) ? bsum[t] : 0;
  sh[t] = v; __syncthreads();
  for (int ofs = 1; ofs < 1024; ofs <<= 1) {
    int add = (t >= ofs) ? sh[t - ofs] : 0;
    __syncthreads();
    sh[t] += add;
    __syncthreads();
  }
  if (t < nb) bsum[t] = sh[t] - v;
}

__global__ void k_scan_final(const int* __restrict__ deg, const int* __restrict__ bsum,
                             int* __restrict__ row_start, int n) {
  __shared__ int sh[1024];
  int t = threadIdx.x;
  int i = blockIdx.x * 1024 + t;
  int v = (i < n) ? deg[i] : 0;
  sh[t] = v; __syncthreads();
  for (int ofs = 1; ofs < 1024; ofs <<= 1) {
    int add = (t >= ofs) ? sh[t - ofs] : 0;
    __syncthreads();
    sh[t] += add;
    __syncthreads();
  }
  if (i < n) {
    row_start[i] = bsum[blockIdx.x] + sh[t] - v;   // exclusive
    if (i == n - 1) row_start[n] = bsum[blockIdx.x] + sh[t];  // total = E
  }
}

__global__ void k_scatter(const int* __restrict__ src, const int* __restrict__ dst,
                          const int* __restrict__ pos, const int* __restrict__ row_start,
                          int* __restrict__ csr_src, int E) {
  int e = blockIdx.x * blockDim.x + threadIdx.x;
  if (e < E) csr_src[row_start[dst[e]] + pos[e]] = src[e];
}

// ---------------- weight pre-swizzle into MFMA fragment order ----------------
// Bswz[s][t][L][j] = bf16( B[s*32 + (L>>4)*8 + j][t*16 + (L&15)] )
__global__ void k_prep(const float* __restrict__ W1, const float* __restrict__ Wmu,
                       const float* __restrict__ Wlv,
                       unsigned short* __restrict__ bswz1,
                       unsigned short* __restrict__ bswz2) {
  int idx = blockIdx.x * 256 + threadIdx.x;
  if (idx < 4096) {            // W1: (256/32)*8*64
    int L = idx & 63, t = (idx >> 6) & 7, s = idx >> 9;
    const float* srcp = W1 + (size_t)(s * 32 + ((L >> 4) << 3)) * 128 + t * 16 + (L & 15);
    unsigned short* dstp = bswz1 + (size_t)idx * 8;
#pragma unroll
    for (int j = 0; j < 8; j++) dstp[j] = f2bf(srcp[(size_t)j * 128]);
  } else if (idx < 6144) {     // [Wmu|Wlv]: (128/32)*8*64
    int id2 = idx - 4096;
    int L = id2 & 63, t = (id2 >> 6) & 7, s = id2 >> 9;
    int nn = t * 16 + (L & 15);
    int k0 = s * 32 + ((L >> 4) << 3);
    const float* W = (nn < C_OUT) ? (Wmu + nn) : (Wlv + (nn - C_OUT));
    unsigned short* dstp = bswz2 + (size_t)id2 * 8;
#pragma unroll
    for (int j = 0; j < 8; j++) dstp[j] = f2bf(W[(size_t)(k0 + j) * C_OUT]);
  }
}

// ---------------- MFMA GEMM: C[M,128](bf16) = A[M,K] @ B[K,128] ----------------
template <typename AT>
__global__ __launch_bounds__(256) void k_gemm_mfma(const AT* __restrict__ A,
                                                   const unsigned short* __restrict__ bswz,
                                                   unsigned short* __restrict__ C,
                                                   int M, int K) {
  int wave = threadIdx.x >> 6, lane = threadIdx.x & 63;
  int m0 = blockIdx.x * 64 + wave * 16;
  int lrow = lane & 15, lq = lane >> 4;
  int arow = m0 + lrow;
  bool rv = arow < M;
  const AT* ap = A + (size_t)(rv ? arow : 0) * K + lq * 8;
  f32x4 acc[8];
#pragma unroll
  for (int t = 0; t < 8; t++) acc[t] = (f32x4){0.f, 0.f, 0.f, 0.f};
  int nsteps = K >> 5;
  for (int s = 0; s < nsteps; ++s) {
    bf16x8 a;
    if (sizeof(AT) == 4) {  // fp32 A -> convert
      const float* af = (const float*)ap + s * 32;
      float4 u0 = rv ? *(const float4*)(af) : float4{0, 0, 0, 0};
      float4 u1 = rv ? *(const float4*)(af + 4) : float4{0, 0, 0, 0};
      union { unsigned short us[8]; bf16x8 v; } tmp;
      tmp.us[0] = f2bf(u0.x); tmp.us[1] = f2bf(u0.y);
      tmp.us[2] = f2bf(u0.z); tmp.us[3] = f2bf(u0.w);
      tmp.us[4] = f2bf(u1.x); tmp.us[5] = f2bf(u1.y);
      tmp.us[6] = f2bf(u1.z); tmp.us[7] = f2bf(u1.w);
      a = tmp.v;
    } else {               // bf16 A
      const unsigned short* ab = (const unsigned short*)ap + s * 32;
      a = rv ? *(const bf16x8*)(ab) : (bf16x8)(short)0;
    }
    const unsigned short* bp = bswz + (size_t)s * 4096 + lane * 8;
#pragma unroll
    for (int t = 0; t < 8; t++) {
      bf16x8 b = *(const bf16x8*)(bp + t * 512);
      acc[t] = __builtin_amdgcn_mfma_f32_16x16x32_bf16(a, b, acc[t], 0, 0, 0);
    }
  }
#pragma unroll
  for (int i = 0; i < 4; i++) {
    int rr = m0 + lq * 4 + i;
    if (rr < M) {
      unsigned short* cp = C + (size_t)rr * 128 + lrow;
#pragma unroll
      for (int t = 0; t < 8; t++) cp[t * 16] = f2bf(acc[t][i]);
    }
  }
}

// ---------------- gather aggregation: half-wave per edge ----------------------
// lanes 0-31 handle even edge of a pair, 32-63 the odd edge; each lane loads
// uint2 = 4 bf16 features [4*hl .. 4*hl+3]. Final __shfl_xor(32) merges halves.
#define AGG_BODY                                                                    \
  int wid = (blockIdx.x * blockDim.x + threadIdx.x) >> 6;                           \
  int lane = threadIdx.x & 63;                                                      \
  if (wid >= n) return;                                                             \
  int half = lane >> 5;                                                             \
  int hl = lane & 31;                                                               \
  int rs = row_start[wid], re = row_start[wid + 1];                                 \
  float a0 = 0.f, a1 = 0.f, a2 = 0.f, a3 = 0.f;                                     \
  int e = rs;                                                                       \
  for (; e + 16 <= re; e += 16) {                                                   \
    int s[8]; float w[8]; uint2 v[8];                                               \
    _Pragma("unroll")                                                               \
    for (int k = 0; k < 8; k++) s[k] = csr[e + 2 * k + half];                       \
    _Pragma("unroll")                                                               \
    for (int k = 0; k < 8; k++) w[k] = dinv[s[k]];                                  \
    _Pragma("unroll")                                                               \
    for (int k = 0; k < 8; k++)                                                     \
      v[k] = *(const uint2*)(p + (size_t)s[k] * 128 + hl * 4);                      \
    _Pragma("unroll")                                                               \
    for (int k = 0; k < 8; k++) {                                                   \
      a0 += bflo(v[k].x) * w[k]; a1 += bfhi(v[k].x) * w[k];                         \
      a2 += bflo(v[k].y) * w[k]; a3 += bfhi(v[k].y) * w[k];                         \
    }                                                                               \
  }                                                                                 \
  for (; e + 2 <= re; e += 2) {                                                     \
    int s = csr[e + half];                                                          \
    float w = dinv[s];                                                              \
    uint2 v = *(const uint2*)(p + (size_t)s * 128 + hl * 4);                        \
    a0 += bflo(v.x) * w; a1 += bfhi(v.x) * w;                                       \
    a2 += bflo(v.y) * w; a3 += bfhi(v.y) * w;                                       \
  }                                                                                 \
  if (e < re) {  /* odd tail edge: lower half only */                               \
    int s = csr[e];                                                                 \
    float w = half ? 0.f : dinv[s];                                                 \
    uint2 v = *(const uint2*)(p + (size_t)s * 128 + hl * 4);                        \
    a0 += bflo(v.x) * w; a1 += bfhi(v.x) * w;                                       \
    a2 += bflo(v.y) * w; a3 += bfhi(v.y) * w;                                       \
  }                                                                                 \
  float di = dinv[wid];                                                             \
  {  /* self loop: lower half only */                                               \
    float w = half ? 0.f : di;                                                      \
    uint2 v = *(const uint2*)(p + (size_t)wid * 128 + hl * 4);                      \
    a0 += bflo(v.x) * w; a1 += bfhi(v.x) * w;                                       \
    a2 += bflo(v.y) * w; a3 += bfhi(v.y) * w;                                       \
  }                                                                                 \
  a0 += __shfl_xor(a0, 32); a1 += __shfl_xor(a1, 32);                               \
  a2 += __shfl_xor(a2, 32); a3 += __shfl_xor(a3, 32);                               \
  a0 *= di; a1 *= di; a2 *= di; a3 *= di;

__global__ __launch_bounds__(256) void k_agg_relu_bf(
    const unsigned short* __restrict__ p, const float* __restrict__ dinv,
    const int* __restrict__ row_start, const int* __restrict__ csr,
    const float* __restrict__ bias, unsigned short* __restrict__ h, int n) {
  AGG_BODY
  if (half == 0) {
    float4 bb = *(const float4*)(bias + 4 * hl);
    float r0 = fmaxf(a0 + bb.x, 0.f), r1 = fmaxf(a1 + bb.y, 0.f);
    float r2 = fmaxf(a2 + bb.z, 0.f), r3 = fmaxf(a3 + bb.w, 0.f);
    uint2 pk;
    pk.x = (unsigned)f2bf(r0) | ((unsigned)f2bf(r1) << 16);
    pk.y = (unsigned)f2bf(r2) | ((unsigned)f2bf(r3) << 16);
    *(uint2*)(h + (size_t)wid * 128 + 4 * hl) = pk;
  }
}

__global__ __launch_bounds__(256) void k_agg_out_bf(
    const unsigned short* __restrict__ p, const float* __restrict__ dinv,
    const int* __restrict__ row_start, const int* __restrict__ csr,
    const float* __restrict__ bmu, const float* __restrict__ blv,
    float* __restrict__ out, int n) {
  AGG_BODY
  if (half == 0) {
    // features 4hl..4hl+3: hl<16 -> mu cols, hl>=16 -> lv cols
    float4 bb = (hl < 16) ? *(const float4*)(bmu + 4 * hl)
                          : *(const float4*)(blv + 4 * hl - 64);
    float* op = (hl < 16) ? (out + (size_t)wid * C_OUT + 4 * hl)
                          : (out + (size_t)(n + wid) * C_OUT + 4 * hl - 64);
    float4 res = {a0 + bb.x, a1 + bb.y, a2 + bb.z, a3 + bb.w};
    *(float4*)op = res;
  }
}

// ---------------------------------------------------------------------------
extern "C" void kernel_launch(void* const* d_in, const int* in_sizes, int n_in,
                              void* d_out, int out_size, void* d_ws, size_t ws_size,
                              hipStream_t stream) {
  const float* x   = (const float*)d_in[0];
  const int*   ei  = (const int*)d_in[1];   // int32 on the wire (JAX x64 off)
  const float* W1  = (const float*)d_in[2];
  const float* b1  = (const float*)d_in[3];
  const float* Wmu = (const float*)d_in[4];
  const float* bmu = (const float*)d_in[5];
  const float* Wlv = (const float*)d_in[6];
  const float* blv = (const float*)d_in[7];
  float* out = (float*)d_out;

  const int n = in_sizes[0] / C_IN;
  const int E = in_sizes[1] / 2;
  const int* src = ei;
  const int* dst = ei + E;

  char* w = (char*)d_ws;
  auto alloc = [&](size_t bytes) -> void* {
    void* pp = (void*)w;
    w += (bytes + 255) & ~(size_t)255;
    return pp;
  };
  int*            degi      = (int*)alloc((size_t)n * 4);
  float*          dinv      = (float*)alloc((size_t)n * 4);
  int*            row_start = (int*)alloc((size_t)(n + 1) * 4);
  int*            bsum      = (int*)alloc(1024 * 4);
  int*            csr_src   = (int*)alloc((size_t)E * 4);
  int*            pos       = (int*)alloc((size_t)E * 4);
  unsigned short* bswz1     = (unsigned short*)alloc((size_t)C_IN * 128 * 2);
  unsigned short* bswz2     = (unsigned short*)alloc((size_t)HID * 128 * 2);
  unsigned short* p1        = (unsigned short*)alloc((size_t)n * 128 * 2);
  unsigned short* hbuf      = (unsigned short*)alloc((size_t)n * 128 * 2);
  unsigned short* p2        = (unsigned short*)alloc((size_t)n * 128 * 2);
  (void)ws_size; (void)n_in; (void)out_size;

  const int TB = 256;
  const int ebks = (E + TB - 1) / TB;
  const int nbks = (n + TB - 1) / TB;
  const int nb_scan = (n + 1023) / 1024;
  const int gemm_bks = (n + 63) / 64;
  const int agg_bks = (int)(((size_t)n * 64 + TB - 1) / TB);  // one wave per node

  // ---- graph structure ----
  hipMemsetAsync(degi, 0, (size_t)n * 4, stream);
  k_count<<<ebks, TB, 0, stream>>>(dst, degi, pos, E);
  k_dinv<<<nbks, TB, 0, stream>>>(degi, dinv, n);
  k_block_sum<<<nb_scan, 1024, 0, stream>>>(degi, bsum, n);
  k_scan_sums<<<1, 1024, 0, stream>>>(bsum, nb_scan);
  k_scan_final<<<nb_scan, 1024, 0, stream>>>(degi, bsum, row_start, n);
  k_scatter<<<ebks, TB, 0, stream>>>(src, dst, pos, row_start, csr_src, E);
  k_prep<<<24, 256, 0, stream>>>(W1, Wmu, Wlv, bswz1, bswz2);

  // ---- layer 1 ----
  k_gemm_mfma<float><<<gemm_bks, TB, 0, stream>>>(x, bswz1, p1, n, C_IN);
  k_agg_relu_bf<<<agg_bks, TB, 0, stream>>>(p1, dinv, row_start, csr_src, b1, hbuf, n);

  // ---- layer 2+3 fused ----
  k_gemm_mfma<unsigned short><<<gemm_bks, TB, 0, stream>>>(hbuf, bswz2, p2, n, HID);
  k_agg_out_bf<<<agg_bks, TB, 0, stream>>>(p2, dinv, row_start, csr_src, bmu, blv, out, n);
}

// Round 4
// 453.289 us; speedup vs baseline: 1.5386x; 1.0881x over previous
//
#include <hip/hip_runtime.h>

// ---------------------------------------------------------------------------
// GCN encoder, bf16 staging + MFMA GEMMs + readlane-broadcast gather agg.
//   h  = relu(Agg(x@W1) + b1);  [mu|lv] = Agg(h@[Wmu|Wlv]) + bias
// Agg(p)[i] = dinv[i] * ( sum_{e: dst=i} p[src]*dinv[src] + p[i]*dinv[i] )
// Agg: one wave per node. Lane l preloads csr[rs+l] + dinv (one coalesced
// epoch per 64 edges); gather loop gets (s,w) via v_readlane (SGPR, no mem),
// so all feature-row loads are independent -> 8 rows in flight, no tail.
// ---------------------------------------------------------------------------

#define C_IN  256
#define HID   128
#define C_OUT 64

typedef __attribute__((ext_vector_type(8))) short bf16x8;
typedef __attribute__((ext_vector_type(4))) float f32x4;

__device__ inline unsigned short f2bf(float f) {  // round-to-nearest-even
  unsigned u = __float_as_uint(f);
  unsigned r = u + 0x7FFF + ((u >> 16) & 1);
  return (unsigned short)(r >> 16);
}
__device__ inline float bflo(unsigned v) { return __uint_as_float(v << 16); }
__device__ inline float bfhi(unsigned v) { return __uint_as_float(v & 0xFFFF0000u); }

// ---------------- degree count + fill position (one atomic pass) ------------
__global__ void k_count(const int* __restrict__ dst, int* __restrict__ deg,
                        int* __restrict__ pos, int E) {
  int e = blockIdx.x * blockDim.x + threadIdx.x;
  if (e < E) pos[e] = atomicAdd(&deg[dst[e]], 1);
}

__global__ void k_dinv(const int* __restrict__ deg, float* __restrict__ dinv, int n) {
  int i = blockIdx.x * blockDim.x + threadIdx.x;
  if (i < n) dinv[i] = rsqrtf((float)deg[i] + 1.0f);
}

// ---------------- 3-phase exclusive scan of deg -> row_start ----------------
__global__ void k_block_sum(const int* __restrict__ deg, int* __restrict__ bsum, int n) {
  __shared__ int sh[1024];
  int i = blockIdx.x * 1024 + threadIdx.x;
  sh[threadIdx.x] = (i < n) ? deg[i] : 0;
  __syncthreads();
  for (int s = 512; s > 0; s >>= 1) {
    if (threadIdx.x < s) sh[threadIdx.x] += sh[threadIdx.x + s];
    __syncthreads();
  }
  if (threadIdx.x == 0) bsum[blockIdx.x] = sh[0];
}

__global__ void k_scan_sums(int* __restrict__ bsum, int nb) {  // exclusive, in place
  __shared__ int sh[1024];
  int t = threadIdx.x;
  int v = (t < nb) ? bsum[t] : 0;
  sh[t] = v; __syncthreads();
  for (int ofs = 1; ofs < 1024; ofs <<= 1) {
    int add = (t >= ofs) ? sh[t - ofs] : 0;
    __syncthreads();
    sh[t] += add;
    __syncthreads();
  }
  if (t < nb) bsum[t] = sh[t] - v;
}

__global__ void k_scan_final(const int* __restrict__ deg, const int* __restrict__ bsum,
                             int* __restrict__ row_start, int n) {
  __shared__ int sh[1024];
  int t = threadIdx.x;
  int i = blockIdx.x * 1024 + t;
  int v = (i < n) ? deg[i] : 0;
  sh[t] = v; __syncthreads();
  for (int ofs = 1; ofs < 1024; ofs <<= 1) {
    int add = (t >= ofs) ? sh[t - ofs] : 0;
    __syncthreads();
    sh[t] += add;
    __syncthreads();
  }
  if (i < n) {
    row_start[i] = bsum[blockIdx.x] + sh[t] - v;   // exclusive
    if (i == n - 1) row_start[n] = bsum[blockIdx.x] + sh[t];  // total = E
  }
}

__global__ void k_scatter(const int* __restrict__ src, const int* __restrict__ dst,
                          const int* __restrict__ pos, const int* __restrict__ row_start,
                          int* __restrict__ csr_src, int E) {
  int e = blockIdx.x * blockDim.x + threadIdx.x;
  if (e < E) csr_src[row_start[dst[e]] + pos[e]] = src[e];
}

// ---------------- weight pre-swizzle into MFMA fragment order ----------------
// Bswz[s][t][L][j] = bf16( B[s*32 + (L>>4)*8 + j][t*16 + (L&15)] )
__global__ void k_prep(const float* __restrict__ W1, const float* __restrict__ Wmu,
                       const float* __restrict__ Wlv,
                       unsigned short* __restrict__ bswz1,
                       unsigned short* __restrict__ bswz2) {
  int idx = blockIdx.x * 256 + threadIdx.x;
  if (idx < 4096) {            // W1: (256/32)*8*64
    int L = idx & 63, t = (idx >> 6) & 7, s = idx >> 9;
    const float* srcp = W1 + (size_t)(s * 32 + ((L >> 4) << 3)) * 128 + t * 16 + (L & 15);
    unsigned short* dstp = bswz1 + (size_t)idx * 8;
#pragma unroll
    for (int j = 0; j < 8; j++) dstp[j] = f2bf(srcp[(size_t)j * 128]);
  } else if (idx < 6144) {     // [Wmu|Wlv]: (128/32)*8*64
    int id2 = idx - 4096;
    int L = id2 & 63, t = (id2 >> 6) & 7, s = id2 >> 9;
    int nn = t * 16 + (L & 15);
    int k0 = s * 32 + ((L >> 4) << 3);
    const float* W = (nn < C_OUT) ? (Wmu + nn) : (Wlv + (nn - C_OUT));
    unsigned short* dstp = bswz2 + (size_t)id2 * 8;
#pragma unroll
    for (int j = 0; j < 8; j++) dstp[j] = f2bf(W[(size_t)(k0 + j) * C_OUT]);
  }
}

// ---------------- MFMA GEMM: C[M,128](bf16) = A[M,K] @ B[K,128] ----------------
// Full K-unroll (template), explicit s+1 prefetch of A-frag and 8 B-frags so
// global-load epochs overlap the MFMA issue of the current step.
template <typename AT, int K>
__global__ __launch_bounds__(256) void k_gemm_mfma(const AT* __restrict__ A,
                                                   const unsigned short* __restrict__ bswz,
                                                   unsigned short* __restrict__ C,
                                                   int M) {
  constexpr int NS = K / 32;
  int wave = threadIdx.x >> 6, lane = threadIdx.x & 63;
  int m0 = blockIdx.x * 64 + wave * 16;
  int lrow = lane & 15, lq = lane >> 4;
  int arow = m0 + lrow;
  bool rv = arow < M;
  const AT* ap = A + (size_t)(rv ? arow : 0) * K + lq * 8;

  auto loadA = [&](int s) -> bf16x8 {
    if (sizeof(AT) == 4) {
      const float* af = (const float*)ap + s * 32;
      float4 u0 = rv ? *(const float4*)(af) : float4{0, 0, 0, 0};
      float4 u1 = rv ? *(const float4*)(af + 4) : float4{0, 0, 0, 0};
      union { unsigned short us[8]; bf16x8 v; } tmp;
      tmp.us[0] = f2bf(u0.x); tmp.us[1] = f2bf(u0.y);
      tmp.us[2] = f2bf(u0.z); tmp.us[3] = f2bf(u0.w);
      tmp.us[4] = f2bf(u1.x); tmp.us[5] = f2bf(u1.y);
      tmp.us[6] = f2bf(u1.z); tmp.us[7] = f2bf(u1.w);
      return tmp.v;
    } else {
      const unsigned short* ab = (const unsigned short*)ap + s * 32;
      return rv ? *(const bf16x8*)(ab) : (bf16x8)(short)0;
    }
  };

  f32x4 acc[8];
#pragma unroll
  for (int t = 0; t < 8; t++) acc[t] = (f32x4){0.f, 0.f, 0.f, 0.f};

  bf16x8 a_cur = loadA(0);
  bf16x8 b_cur[8];
#pragma unroll
  for (int t = 0; t < 8; t++)
    b_cur[t] = *(const bf16x8*)(bswz + lane * 8 + t * 512);

#pragma unroll
  for (int s = 0; s < NS; ++s) {
    bf16x8 a_nxt = a_cur;
    bf16x8 b_nxt[8];
    if (s + 1 < NS) {
      a_nxt = loadA(s + 1);
      const unsigned short* bp = bswz + (size_t)(s + 1) * 4096 + lane * 8;
#pragma unroll
      for (int t = 0; t < 8; t++) b_nxt[t] = *(const bf16x8*)(bp + t * 512);
    }
#pragma unroll
    for (int t = 0; t < 8; t++)
      acc[t] = __builtin_amdgcn_mfma_f32_16x16x32_bf16(a_cur, b_cur[t], acc[t], 0, 0, 0);
    a_cur = a_nxt;
    if (s + 1 < NS) {
#pragma unroll
      for (int t = 0; t < 8; t++) b_cur[t] = b_nxt[t];
    }
  }
#pragma unroll
  for (int i = 0; i < 4; i++) {
    int rr = m0 + lq * 4 + i;
    if (rr < M) {
      unsigned short* cp = C + (size_t)rr * 128 + lrow;
#pragma unroll
      for (int t = 0; t < 8; t++) cp[t * 16] = f2bf(acc[t][i]);
    }
  }
}

// ---------------- gather aggregation: readlane-broadcast, no tail ------------
// lane l preloads edge (s,w); loop reads them back uniformly via readlane.
// Pad lanes carry (wid, 0): pad loads hit the L1-hot self row with weight 0.
__device__ inline float rdlane_f(float v, int k) {
  return __uint_as_float(__builtin_amdgcn_readlane(__float_as_uint(v), k));
}

#define AGG_BODY                                                                    \
  int wid = (blockIdx.x * blockDim.x + threadIdx.x) >> 6;                           \
  int lane = threadIdx.x & 63;                                                      \
  if (wid >= n) return;                                                             \
  int rs = row_start[wid], re = row_start[wid + 1];                                 \
  float di = dinv[wid];                                                             \
  float acc0 = 0.f, acc1 = 0.f;                                                     \
  for (int base = rs; base < re + 1; base += 64) {                                  \
    int idx = base + lane;                                                          \
    int sl = wid; float wl = 0.f;                                                   \
    if (idx < re) { sl = csr[idx]; wl = dinv[sl]; }                                 \
    else if (idx == re) { wl = di; }  /* self edge */                               \
    int m = re + 1 - base; if (m > 64) m = 64;                                      \
    int mr = (m + 7) & ~7;            /* <= 64 */                                   \
    for (int k = 0; k < mr; k += 8) {                                               \
      _Pragma("unroll")                                                             \
      for (int j = 0; j < 8; j++) {                                                 \
        int kk = k + j;                                                             \
        int sk = __builtin_amdgcn_readlane(sl, kk);                                 \
        float wk = rdlane_f(wl, kk);                                                \
        unsigned v = *(const unsigned*)(p + (size_t)sk * 128 + 2 * lane);           \
        acc0 += bflo(v) * wk;                                                       \
        acc1 += bfhi(v) * wk;                                                       \
      }                                                                             \
    }                                                                               \
  }                                                                                 \
  acc0 *= di; acc1 *= di;

__global__ __launch_bounds__(256) void k_agg_relu_bf(
    const unsigned short* __restrict__ p, const float* __restrict__ dinv,
    const int* __restrict__ row_start, const int* __restrict__ csr,
    const float* __restrict__ bias, unsigned short* __restrict__ h, int n) {
  AGG_BODY
  float2 bb = *(const float2*)(bias + 2 * lane);
  float r0 = fmaxf(acc0 + bb.x, 0.f);
  float r1 = fmaxf(acc1 + bb.y, 0.f);
  unsigned pk = (unsigned)f2bf(r0) | ((unsigned)f2bf(r1) << 16);
  *(unsigned*)(h + (size_t)wid * 128 + 2 * lane) = pk;
}

__global__ __launch_bounds__(256) void k_agg_out_bf(
    const unsigned short* __restrict__ p, const float* __restrict__ dinv,
    const int* __restrict__ row_start, const int* __restrict__ csr,
    const float* __restrict__ bmu, const float* __restrict__ blv,
    float* __restrict__ out, int n) {
  AGG_BODY
  // lane cols 2L,2L+1: L<32 -> mu, L>=32 -> lv
  float2 bb = (lane < 32) ? *(const float2*)(bmu + 2 * lane)
                          : *(const float2*)(blv + 2 * lane - 64);
  float* op = (lane < 32) ? (out + (size_t)wid * C_OUT + 2 * lane)
                          : (out + (size_t)(n + wid) * C_OUT + 2 * lane - 64);
  float2 res = {acc0 + bb.x, acc1 + bb.y};
  *(float2*)op = res;
}

// ---------------------------------------------------------------------------
extern "C" void kernel_launch(void* const* d_in, const int* in_sizes, int n_in,
                              void* d_out, int out_size, void* d_ws, size_t ws_size,
                              hipStream_t stream) {
  const float* x   = (const float*)d_in[0];
  const int*   ei  = (const int*)d_in[1];   // int32 on the wire (JAX x64 off)
  const float* W1  = (const float*)d_in[2];
  const float* b1  = (const float*)d_in[3];
  const float* Wmu = (const float*)d_in[4];
  const float* bmu = (const float*)d_in[5];
  const float* Wlv = (const float*)d_in[6];
  const float* blv = (const float*)d_in[7];
  float* out = (float*)d_out;

  const int n = in_sizes[0] / C_IN;
  const int E = in_sizes[1] / 2;
  const int* src = ei;
  const int* dst = ei + E;

  char* w = (char*)d_ws;
  auto alloc = [&](size_t bytes) -> void* {
    void* pp = (void*)w;
    w += (bytes + 255) & ~(size_t)255;
    return pp;
  };
  int*            degi      = (int*)alloc((size_t)n * 4);
  float*          dinv      = (float*)alloc((size_t)n * 4);
  int*            row_start = (int*)alloc((size_t)(n + 1) * 4);
  int*            bsum      = (int*)alloc(1024 * 4);
  int*            csr_src   = (int*)alloc((size_t)E * 4);
  int*            pos       = (int*)alloc((size_t)E * 4);
  unsigned short* bswz1     = (unsigned short*)alloc((size_t)C_IN * 128 * 2);
  unsigned short* bswz2     = (unsigned short*)alloc((size_t)HID * 128 * 2);
  unsigned short* p1        = (unsigned short*)alloc((size_t)n * 128 * 2);
  unsigned short* hbuf      = (unsigned short*)alloc((size_t)n * 128 * 2);
  unsigned short* p2        = (unsigned short*)alloc((size_t)n * 128 * 2);
  (void)ws_size; (void)n_in; (void)out_size;

  const int TB = 256;
  const int ebks = (E + TB - 1) / TB;
  const int nbks = (n + TB - 1) / TB;
  const int nb_scan = (n + 1023) / 1024;
  const int gemm_bks = (n + 63) / 64;
  const int agg_bks = (int)(((size_t)n * 64 + TB - 1) / TB);  // one wave per node

  // ---- graph structure ----
  hipMemsetAsync(degi, 0, (size_t)n * 4, stream);
  k_count<<<ebks, TB, 0, stream>>>(dst, degi, pos, E);
  k_dinv<<<nbks, TB, 0, stream>>>(degi, dinv, n);
  k_block_sum<<<nb_scan, 1024, 0, stream>>>(degi, bsum, n);
  k_scan_sums<<<1, 1024, 0, stream>>>(bsum, nb_scan);
  k_scan_final<<<nb_scan, 1024, 0, stream>>>(degi, bsum, row_start, n);
  k_scatter<<<ebks, TB, 0, stream>>>(src, dst, pos, row_start, csr_src, E);
  k_prep<<<24, 256, 0, stream>>>(W1, Wmu, Wlv, bswz1, bswz2);

  // ---- layer 1 ----
  k_gemm_mfma<float, C_IN><<<gemm_bks, TB, 0, stream>>>(x, bswz1, p1, n);
  k_agg_relu_bf<<<agg_bks, TB, 0, stream>>>(p1, dinv, row_start, csr_src, b1, hbuf, n);

  // ---- layer 2+3 fused ----
  k_gemm_mfma<unsigned short, HID><<<gemm_bks, TB, 0, stream>>>(hbuf, bswz2, p2, n);
  k_agg_out_bf<<<agg_bks, TB, 0, stream>>>(p2, dinv, row_start, csr_src, bmu, blv, out, n);
}

// Round 5
// 406.150 us; speedup vs baseline: 1.7172x; 1.1161x over previous
//
#include <hip/hip_runtime.h>

// ---------------------------------------------------------------------------
// GCN encoder, bf16 staging + MFMA GEMMs + readlane-broadcast gather agg.
//   h  = relu(Agg(x@W1) + b1);  [mu|lv] = Agg(h@[Wmu|Wlv]) + bias
// Agg(p)[i] = dinv[i] * ( sum_{e: dst=i} p[src]*dinv[src] + p[i]*dinv[i] )
// CSR build: LDS radix binning (bucket = dst>>7, 1024 buckets x 128 nodes),
// zero global atomics (they resolve memory-side on MI355X: 1.6M random
// atomicAdds measured 68 us, WRITE_SIZE 56MB ~= 32B/op). All atomics -> LDS.
// Requires n <= 131072 (n = 100000 here).
// ---------------------------------------------------------------------------

#define C_IN  256
#define HID   128
#define C_OUT 64
#define NBUCK 1024
#define P1WGS 256

typedef __attribute__((ext_vector_type(8))) short bf16x8;
typedef __attribute__((ext_vector_type(4))) float f32x4;

__device__ inline unsigned short f2bf(float f) {  // round-to-nearest-even
  unsigned u = __float_as_uint(f);
  unsigned r = u + 0x7FFF + ((u >> 16) & 1);
  return (unsigned short)(r >> 16);
}
__device__ inline float bflo(unsigned v) { return __uint_as_float(v << 16); }
__device__ inline float bfhi(unsigned v) { return __uint_as_float(v & 0xFFFF0000u); }

// ---------------- P1: per-WG bucket histogram (LDS atomics only) -------------
__global__ __launch_bounds__(256) void k_bin_count(const int* __restrict__ dst,
                                                   int* __restrict__ histmat, int E) {
  __shared__ int h[NBUCK];
  int tid = threadIdx.x;
  for (int i = tid; i < NBUCK; i += 256) h[i] = 0;
  __syncthreads();
  for (int e = blockIdx.x * 256 + tid; e < E; e += P1WGS * 256)
    atomicAdd(&h[dst[e] >> 7], 1);
  __syncthreads();
  for (int i = tid; i < NBUCK; i += 256)
    histmat[blockIdx.x * NBUCK + i] = h[i];
}

// ---------------- P2: per-bucket exclusive scan across WGs (in place) --------
__global__ __launch_bounds__(256) void k_col_scan(int* __restrict__ histmat,
                                                  int* __restrict__ bucket_tot) {
  __shared__ int sh[P1WGS];
  int b = blockIdx.x;
  int t = threadIdx.x;
  int v = histmat[t * NBUCK + b];
  sh[t] = v; __syncthreads();
  for (int ofs = 1; ofs < P1WGS; ofs <<= 1) {
    int add = (t >= ofs) ? sh[t - ofs] : 0;
    __syncthreads();
    sh[t] += add;
    __syncthreads();
  }
  histmat[t * NBUCK + b] = sh[t] - v;  // exclusive
  if (t == P1WGS - 1) bucket_tot[b] = sh[t];
}

// ---------------- P3: bucket_start = exclusive scan of bucket_tot ------------
__global__ void k_bucket_scan(const int* __restrict__ bucket_tot,
                              int* __restrict__ bucket_start, int E) {
  __shared__ int sh[NBUCK];
  int t = threadIdx.x;
  int v = bucket_tot[t];
  sh[t] = v; __syncthreads();
  for (int ofs = 1; ofs < NBUCK; ofs <<= 1) {
    int add = (t >= ofs) ? sh[t - ofs] : 0;
    __syncthreads();
    sh[t] += add;
    __syncthreads();
  }
  bucket_start[t] = sh[t] - v;
  if (t == NBUCK - 1) bucket_start[NBUCK] = E;
}

// ---------------- P4: scatter edges into bucket-segmented array --------------
// pack: src (17 bits) | local-node (7 bits) << 17.  Each WG's writes to a
// bucket are a private sequential sub-segment -> no global atomics.
__global__ __launch_bounds__(256) void k_bin_scatter(const int* __restrict__ src,
                                                     const int* __restrict__ dst,
                                                     const int* __restrict__ histmat,
                                                     const int* __restrict__ bucket_start,
                                                     unsigned* __restrict__ binned, int E) {
  __shared__ int cur[NBUCK];
  int tid = threadIdx.x;
  for (int i = tid; i < NBUCK; i += 256)
    cur[i] = bucket_start[i] + histmat[blockIdx.x * NBUCK + i];
  __syncthreads();
  for (int e = blockIdx.x * 256 + tid; e < E; e += P1WGS * 256) {
    int d = dst[e];
    int pos = atomicAdd(&cur[d >> 7], 1);
    binned[pos] = (unsigned)src[e] | ((unsigned)(d & 127) << 17);
  }
}

// ---------------- P5: per-bucket deg/dinv/row_start + CSR fill ---------------
__global__ __launch_bounds__(256) void k_bucket_csr(const unsigned* __restrict__ binned,
                                                    const int* __restrict__ bucket_start,
                                                    int* __restrict__ row_start,
                                                    float* __restrict__ dinv,
                                                    int* __restrict__ csr_src,
                                                    int n, int E) {
  __shared__ int h[128], ls[128], c[128];
  int b = blockIdx.x, t = threadIdx.x;
  int start = bucket_start[b], end = bucket_start[b + 1];
  if (t < 128) h[t] = 0;
  __syncthreads();
  for (int e = start + t; e < end; e += 256)
    atomicAdd(&h[binned[e] >> 17], 1);
  __syncthreads();
  if (t < 128) ls[t] = h[t];
  __syncthreads();
  for (int ofs = 1; ofs < 128; ofs <<= 1) {
    int add = (t < 128 && t >= ofs) ? ls[t - ofs] : 0;
    __syncthreads();
    if (t < 128) ls[t] += add;
    __syncthreads();
  }
  if (t < 128) {
    int excl = ls[t] - h[t];
    ls[t] = excl;
    c[t] = excl;
    int node = b * 128 + t;
    if (node < n) {
      row_start[node] = start + excl;
      dinv[node] = rsqrtf((float)h[t] + 1.0f);
    }
  }
  if (b == 0 && t == 0) row_start[n] = E;
  __syncthreads();
  for (int e = start + t; e < end; e += 256) {
    unsigned v = binned[e];
    int pos = start + atomicAdd(&c[v >> 17], 1);
    csr_src[pos] = (int)(v & 0x1FFFF);
  }
}

// ---------------- weight pre-swizzle into MFMA fragment order ----------------
// Bswz[s][t][L][j] = bf16( B[s*32 + (L>>4)*8 + j][t*16 + (L&15)] )
__global__ void k_prep(const float* __restrict__ W1, const float* __restrict__ Wmu,
                       const float* __restrict__ Wlv,
                       unsigned short* __restrict__ bswz1,
                       unsigned short* __restrict__ bswz2) {
  int idx = blockIdx.x * 256 + threadIdx.x;
  if (idx < 4096) {            // W1: (256/32)*8*64
    int L = idx & 63, t = (idx >> 6) & 7, s = idx >> 9;
    const float* srcp = W1 + (size_t)(s * 32 + ((L >> 4) << 3)) * 128 + t * 16 + (L & 15);
    unsigned short* dstp = bswz1 + (size_t)idx * 8;
#pragma unroll
    for (int j = 0; j < 8; j++) dstp[j] = f2bf(srcp[(size_t)j * 128]);
  } else if (idx < 6144) {     // [Wmu|Wlv]: (128/32)*8*64
    int id2 = idx - 4096;
    int L = id2 & 63, t = (id2 >> 6) & 7, s = id2 >> 9;
    int nn = t * 16 + (L & 15);
    int k0 = s * 32 + ((L >> 4) << 3);
    const float* W = (nn < C_OUT) ? (Wmu + nn) : (Wlv + (nn - C_OUT));
    unsigned short* dstp = bswz2 + (size_t)id2 * 8;
#pragma unroll
    for (int j = 0; j < 8; j++) dstp[j] = f2bf(W[(size_t)(k0 + j) * C_OUT]);
  }
}

// ---------------- MFMA GEMM: C[M,128](bf16) = A[M,K] @ B[K,128] ----------------
template <typename AT, int K>
__global__ __launch_bounds__(256) void k_gemm_mfma(const AT* __restrict__ A,
                                                   const unsigned short* __restrict__ bswz,
                                                   unsigned short* __restrict__ C,
                                                   int M) {
  constexpr int NS = K / 32;
  int wave = threadIdx.x >> 6, lane = threadIdx.x & 63;
  int m0 = blockIdx.x * 64 + wave * 16;
  int lrow = lane & 15, lq = lane >> 4;
  int arow = m0 + lrow;
  bool rv = arow < M;
  const AT* ap = A + (size_t)(rv ? arow : 0) * K + lq * 8;

  auto loadA = [&](int s) -> bf16x8 {
    if (sizeof(AT) == 4) {
      const float* af = (const float*)ap + s * 32;
      float4 u0 = rv ? *(const float4*)(af) : float4{0, 0, 0, 0};
      float4 u1 = rv ? *(const float4*)(af + 4) : float4{0, 0, 0, 0};
      union { unsigned short us[8]; bf16x8 v; } tmp;
      tmp.us[0] = f2bf(u0.x); tmp.us[1] = f2bf(u0.y);
      tmp.us[2] = f2bf(u0.z); tmp.us[3] = f2bf(u0.w);
      tmp.us[4] = f2bf(u1.x); tmp.us[5] = f2bf(u1.y);
      tmp.us[6] = f2bf(u1.z); tmp.us[7] = f2bf(u1.w);
      return tmp.v;
    } else {
      const unsigned short* ab = (const unsigned short*)ap + s * 32;
      return rv ? *(const bf16x8*)(ab) : (bf16x8)(short)0;
    }
  };

  f32x4 acc[8];
#pragma unroll
  for (int t = 0; t < 8; t++) acc[t] = (f32x4){0.f, 0.f, 0.f, 0.f};

  bf16x8 a_cur = loadA(0);
  bf16x8 b_cur[8];
#pragma unroll
  for (int t = 0; t < 8; t++)
    b_cur[t] = *(const bf16x8*)(bswz + lane * 8 + t * 512);

#pragma unroll
  for (int s = 0; s < NS; ++s) {
    bf16x8 a_nxt = a_cur;
    bf16x8 b_nxt[8];
    if (s + 1 < NS) {
      a_nxt = loadA(s + 1);
      const unsigned short* bp = bswz + (size_t)(s + 1) * 4096 + lane * 8;
#pragma unroll
      for (int t = 0; t < 8; t++) b_nxt[t] = *(const bf16x8*)(bp + t * 512);
    }
#pragma unroll
    for (int t = 0; t < 8; t++)
      acc[t] = __builtin_amdgcn_mfma_f32_16x16x32_bf16(a_cur, b_cur[t], acc[t], 0, 0, 0);
    a_cur = a_nxt;
    if (s + 1 < NS) {
#pragma unroll
      for (int t = 0; t < 8; t++) b_cur[t] = b_nxt[t];
    }
  }
#pragma unroll
  for (int i = 0; i < 4; i++) {
    int rr = m0 + lq * 4 + i;
    if (rr < M) {
      unsigned short* cp = C + (size_t)rr * 128 + lrow;
#pragma unroll
      for (int t = 0; t < 8; t++) cp[t * 16] = f2bf(acc[t][i]);
    }
  }
}

// ---------------- gather aggregation: readlane-broadcast, no tail ------------
__device__ inline float rdlane_f(float v, int k) {
  return __uint_as_float(__builtin_amdgcn_readlane(__float_as_uint(v), k));
}

#define AGG_BODY                                                                    \
  int wid = (blockIdx.x * blockDim.x + threadIdx.x) >> 6;                           \
  int lane = threadIdx.x & 63;                                                      \
  if (wid >= n) return;                                                             \
  int rs = row_start[wid], re = row_start[wid + 1];                                 \
  float di = dinv[wid];                                                             \
  float acc0 = 0.f, acc1 = 0.f;                                                     \
  for (int base = rs; base < re + 1; base += 64) {                                  \
    int idx = base + lane;                                                          \
    int sl = wid; float wl = 0.f;                                                   \
    if (idx < re) { sl = csr[idx]; wl = dinv[sl]; }                                 \
    else if (idx == re) { wl = di; }  /* self edge */                               \
    int m = re + 1 - base; if (m > 64) m = 64;                                      \
    int mr = (m + 7) & ~7;            /* <= 64 */                                   \
    for (int k = 0; k < mr; k += 8) {                                               \
      _Pragma("unroll")                                                             \
      for (int j = 0; j < 8; j++) {                                                 \
        int kk = k + j;                                                             \
        int sk = __builtin_amdgcn_readlane(sl, kk);                                 \
        float wk = rdlane_f(wl, kk);                                                \
        unsigned v = *(const unsigned*)(p + (size_t)sk * 128 + 2 * lane);           \
        acc0 += bflo(v) * wk;                                                       \
        acc1 += bfhi(v) * wk;                                                       \
      }                                                                             \
    }                                                                               \
  }                                                                                 \
  acc0 *= di; acc1 *= di;

__global__ __launch_bounds__(256) void k_agg_relu_bf(
    const unsigned short* __restrict__ p, const float* __restrict__ dinv,
    const int* __restrict__ row_start, const int* __restrict__ csr,
    const float* __restrict__ bias, unsigned short* __restrict__ h, int n) {
  AGG_BODY
  float2 bb = *(const float2*)(bias + 2 * lane);
  float r0 = fmaxf(acc0 + bb.x, 0.f);
  float r1 = fmaxf(acc1 + bb.y, 0.f);
  unsigned pk = (unsigned)f2bf(r0) | ((unsigned)f2bf(r1) << 16);
  *(unsigned*)(h + (size_t)wid * 128 + 2 * lane) = pk;
}

__global__ __launch_bounds__(256) void k_agg_out_bf(
    const unsigned short* __restrict__ p, const float* __restrict__ dinv,
    const int* __restrict__ row_start, const int* __restrict__ csr,
    const float* __restrict__ bmu, const float* __restrict__ blv,
    float* __restrict__ out, int n) {
  AGG_BODY
  float2 bb = (lane < 32) ? *(const float2*)(bmu + 2 * lane)
                          : *(const float2*)(blv + 2 * lane - 64);
  float* op = (lane < 32) ? (out + (size_t)wid * C_OUT + 2 * lane)
                          : (out + (size_t)(n + wid) * C_OUT + 2 * lane - 64);
  float2 res = {acc0 + bb.x, acc1 + bb.y};
  *(float2*)op = res;
}

// ---------------------------------------------------------------------------
extern "C" void kernel_launch(void* const* d_in, const int* in_sizes, int n_in,
                              void* d_out, int out_size, void* d_ws, size_t ws_size,
                              hipStream_t stream) {
  const float* x   = (const float*)d_in[0];
  const int*   ei  = (const int*)d_in[1];   // int32 on the wire (JAX x64 off)
  const float* W1  = (const float*)d_in[2];
  const float* b1  = (const float*)d_in[3];
  const float* Wmu = (const float*)d_in[4];
  const float* bmu = (const float*)d_in[5];
  const float* Wlv = (const float*)d_in[6];
  const float* blv = (const float*)d_in[7];
  float* out = (float*)d_out;

  const int n = in_sizes[0] / C_IN;
  const int E = in_sizes[1] / 2;
  const int* src = ei;
  const int* dst = ei + E;

  char* w = (char*)d_ws;
  auto alloc = [&](size_t bytes) -> void* {
    void* pp = (void*)w;
    w += (bytes + 255) & ~(size_t)255;
    return pp;
  };
  float*          dinv       = (float*)alloc((size_t)n * 4);
  int*            row_start  = (int*)alloc((size_t)(n + 1) * 4);
  int*            histmat    = (int*)alloc((size_t)P1WGS * NBUCK * 4);
  int*            bucket_tot = (int*)alloc((size_t)NBUCK * 4);
  int*            bucket_st  = (int*)alloc((size_t)(NBUCK + 1) * 4);
  unsigned*       binned     = (unsigned*)alloc((size_t)E * 4);
  int*            csr_src    = (int*)alloc((size_t)E * 4);
  unsigned short* bswz1      = (unsigned short*)alloc((size_t)C_IN * 128 * 2);
  unsigned short* bswz2      = (unsigned short*)alloc((size_t)HID * 128 * 2);
  unsigned short* p1         = (unsigned short*)alloc((size_t)n * 128 * 2);
  unsigned short* hbuf       = (unsigned short*)alloc((size_t)n * 128 * 2);
  unsigned short* p2         = (unsigned short*)alloc((size_t)n * 128 * 2);
  (void)ws_size; (void)n_in; (void)out_size;

  const int TB = 256;
  const int gemm_bks = (n + 63) / 64;
  const int agg_bks = (int)(((size_t)n * 64 + TB - 1) / TB);  // one wave per node
  const int nbk_csr = (n + 127) / 128;                        // buckets w/ valid nodes

  // ---- CSR build: LDS radix binning, no global atomics ----
  k_bin_count<<<P1WGS, TB, 0, stream>>>(dst, histmat, E);
  k_col_scan<<<NBUCK, TB, 0, stream>>>(histmat, bucket_tot);
  k_bucket_scan<<<1, NBUCK, 0, stream>>>(bucket_tot, bucket_st, E);
  k_bin_scatter<<<P1WGS, TB, 0, stream>>>(src, dst, histmat, bucket_st, binned, E);
  k_bucket_csr<<<nbk_csr, TB, 0, stream>>>(binned, bucket_st, row_start, dinv,
                                           csr_src, n, E);

  // ---- weight pre-swizzle ----
  k_prep<<<24, 256, 0, stream>>>(W1, Wmu, Wlv, bswz1, bswz2);

  // ---- layer 1 ----
  k_gemm_mfma<float, C_IN><<<gemm_bks, TB, 0, stream>>>(x, bswz1, p1, n);
  k_agg_relu_bf<<<agg_bks, TB, 0, stream>>>(p1, dinv, row_start, csr_src, b1, hbuf, n);

  // ---- layer 2+3 fused ----
  k_gemm_mfma<unsigned short, HID><<<gemm_bks, TB, 0, stream>>>(hbuf, bswz2, p2, n);
  k_agg_out_bf<<<agg_bks, TB, 0, stream>>>(p2, dinv, row_start, csr_src, bmu, blv, out, n);
}